// Round 1
// 251.909 us; speedup vs baseline: 1.1009x; 1.1009x over previous
//
#include <hip/hip_runtime.h>
#include <hip/hip_bf16.h>
#include <math.h>

// Problem constants
#define D_DIM 128
#define M_CODES 2048
#define BN_TOT 65536           // B*N = 16*4096
#define OUT_LOSS 8388608       // flat offset of loss
#define OUT_PERP 8388609       // flat offset of perp
#define OUT_IDX 8388610        // flat offset of indices
#define MARGIN 2e-3f           // covers ref fp32 noise (~1.6e-5) + bf16-split err

#define QB 64                  // queries per argmin block (2 q-waves share B via LDS)

// ws byte offsets
#define WS_L2K 0               // float l2k[2048]              (8 KB)
#define WS_PHI 8192            // bf16 packed_hi[32768*8]      (512 KB, MFMA-fragment order)
#define WS_PLO 532480          // bf16 packed_lo[32768*8]      (512 KB)
#define WS_IDX 1056768         // int best_idx[65536]          (256 KB)
#define WS_PART 1318912        // float loss_part[8192]        (32 KB)
#define WS_CNT 1351680         // int counts[2048]             (8 KB)
#define WS_FLAGCNT 1359872     // int flag_count               (pad to 1 KB)
#define WS_FLAGGED 1360896     // int flagged[65536]           (256 KB)

typedef __bf16 bf16x8 __attribute__((ext_vector_type(8)));
typedef float f32x4 __attribute__((ext_vector_type(4)));

// async 16B/lane global->LDS copy: LDS dest is wave-uniform base + lane*16
#define GLOAD_LDS16(g, l)                                         \
  __builtin_amdgcn_global_load_lds(                               \
      (const __attribute__((address_space(1))) void*)(g),         \
      (__attribute__((address_space(3))) void*)(l), 16, 0, 0)

// ---------------------------------------------------------------------------
// Emulated-np ||k||^2: terms rounded to fp32 (w*w), summed in fp64, rounded
// back to fp32 (matches the reference's fp32 sum within ~1 ulp).
// ---------------------------------------------------------------------------
__global__ __launch_bounds__(256) void l2_kernel(const float* __restrict__ w,
                                                 float* __restrict__ l2k) {
  int i = blockIdx.x * 256 + threadIdx.x;
  const float4* p = (const float4*)(w + (size_t)i * D_DIM);
  double s = 0.0;
#pragma unroll
  for (int j = 0; j < 32; ++j) {
    float4 v = p[j];
    s += (double)(v.x * v.x);
    s += (double)(v.y * v.y);
    s += (double)(v.z * v.z);
    s += (double)(v.w * v.w);
  }
  l2k[i] = (float)s;
}

// ---------------------------------------------------------------------------
// Prepack codebook to hi/lo bf16 in MFMA-FRAGMENT ORDER so both the LDS
// staging (global_load_lds: uniform base + lane*16B) and the ds_read_b128
// fragment reads are perfectly linear / conflict-free.
// granule gid = ((c64*16 + ks*4 + nt)*64 + lane), lane=(quad*16+col):
//   data = w[code = c64*64 + nt*16 + col][ks*32 + quad*8 .. +8]
// ---------------------------------------------------------------------------
__global__ __launch_bounds__(256) void pack_w_frag(const float* __restrict__ w,
                                                   __bf16* __restrict__ phi,
                                                   __bf16* __restrict__ plo) {
  int gid = blockIdx.x * 256 + threadIdx.x;  // granule id, 32768 total
  int lane = gid & 63;
  int t = gid >> 6;
  int nt = t & 3;
  int ks = (t >> 2) & 3;
  int c64 = t >> 4;                          // 0..31
  int code = c64 * 64 + nt * 16 + (lane & 15);
  int koff = ks * 32 + (lane >> 4) * 8;
  const float* src = w + (size_t)code * D_DIM + koff;
  float4 u = *(const float4*)src;
  float4 v = *(const float4*)(src + 4);
  float f[8] = {u.x, u.y, u.z, u.w, v.x, v.y, v.z, v.w};
  bf16x8 h, l;
#pragma unroll
  for (int j = 0; j < 8; ++j) {
    __bf16 hh = (__bf16)f[j];
    h[j] = hh;
    l[j] = (__bf16)(f[j] - (float)hh);
  }
  *(bf16x8*)(phi + (size_t)gid * 8) = h;
  *(bf16x8*)(plo + (size_t)gid * 8) = l;
}

// merge (ob,os,oi) into (b,s,i): best+second-best with first-index tie-break
__device__ __forceinline__ void merge_bs(float& b, float& s, int& i,
                                         float ob, float os, int oi) {
  if (ob < b) {
    s = fminf(b, os);
    b = ob;
    i = oi;
  } else if (ob > b) {
    s = fminf(s, ob);
  } else {           // tie: gap 0 -> flagged -> fixup resolves exactly
    s = b;
    if (oi < i) i = oi;
  }
}

// ---------------------------------------------------------------------------
// MFMA argmin v2: dist = l2k - 2*q.k via split-bf16 (hi/lo) 16x16x32 MFMA.
// Block = 256 threads (4 waves) covering 64 queries x ALL 2048 codes.
// Wave grid: wq = wv>>1 (query half, 32 q each), wc = wv&1 (16-code slice).
//
// vs v1 (150 us, MfmaUtil 29%, Occupancy 21%):
//  - B goes through LDS (global_load_lds, dbuf 2x16KB) instead of 128 live
//    VGPRs -> register pressure ~130, 3-4 blocks/CU co-resident (was ~2
//    waves/SIMD).
//  - QB 32->64: the two q-waves share each staged B chunk -> L2 codebook
//    traffic halves (2.15 GB -> 1.07 GB), removing the L2-BW co-limit.
//  - A fragments (32q x 128k hi/lo per wave) live in 64 VGPRs, loaded once
//    coalesced; no per-chunk A ds_reads.
// Chunk = 32 codes = 16 granules of 1KB (8 hi + 8 lo); 64 chunks; 2-phase
// pipeline: issue next-chunk stage, then ds_read+MFMA current, one barrier
// per chunk (barrier's vmcnt drain completes the stage).
// ---------------------------------------------------------------------------
__global__ __launch_bounds__(256, 3) void argmin_mfma(
    const float* __restrict__ x, const __bf16* __restrict__ phi,
    const __bf16* __restrict__ plo, const float* __restrict__ l2k,
    int* __restrict__ best_idx, int* __restrict__ flag_count,
    int* __restrict__ flagged) {
  __shared__ __align__(16) unsigned char ldsB[2][16 * 1024];
  __shared__ float redB[4][32];
  __shared__ float redS[4][32];
  __shared__ int redI[4][32];

  const int tid = threadIdx.x;
  const int wv = tid >> 6;        // wave 0..3
  const int lane = tid & 63;
  const int col = lane & 15;      // MFMA n-index / A m-index
  const int quad = lane >> 4;     // 0..3
  const int wc = wv & 1;          // code-slice within chunk (nt' = wc)
  const int wq = wv >> 1;         // query half (32 q each)
  const int q0 = blockIdx.x * QB;

  // ---- A fragments for this wave's 32 queries, fp32 -> hi/lo bf16, in regs.
  // lane (col,quad) holds x[q0+wq*32+16mt+col][32ks+8quad .. +8] (same
  // per-lane mapping as v1's LDS path; numerics identical).
  bf16x8 ah[2][4], al[2][4];
#pragma unroll
  for (int mt = 0; mt < 2; ++mt) {
#pragma unroll
    for (int ks = 0; ks < 4; ++ks) {
      const float* xr =
          x + (size_t)(q0 + wq * 32 + 16 * mt + col) * D_DIM + 32 * ks + 8 * quad;
      float4 u = *(const float4*)xr;
      float4 v = *(const float4*)(xr + 4);
      float f[8] = {u.x, u.y, u.z, u.w, v.x, v.y, v.z, v.w};
      bf16x8 h, l;
#pragma unroll
      for (int j = 0; j < 8; ++j) {
        __bf16 hh = (__bf16)f[j];
        h[j] = hh;
        l[j] = (__bf16)(f[j] - (float)hh);
      }
      ah[mt][ks] = h;
      al[mt][ks] = l;
    }
  }

  // per-lane running argmin state: query = q0 + wq*32 + 16*mt + 4*quad + r
  float m1[2][4], m2[2][4];
  int bi[2][4];
#pragma unroll
  for (int mt = 0; mt < 2; ++mt)
#pragma unroll
    for (int r = 0; r < 4; ++r) {
      m1[mt][r] = 3.4e38f;
      m2[mt][r] = 3.4e38f;
      bi[mt][r] = 0;
    }

  // ---- Stage chunk ch (32 codes: granules c64*16 + ks*4 + ntb + nt') into
  // ldsB[buf]. 16 granule-copies, 4 per wave, each one global_load_lds of
  // 64 lanes x 16B. cid<8: hi (ks=k2>>1, nt'=k2&1); cid>=8: lo.
  auto stage = [&](int ch, int buf) {
    const int c64 = ch >> 1;
    const int ntb = (ch & 1) * 2;
#pragma unroll
    for (int i = 0; i < 4; ++i) {
      int cid = wv * 4 + i;
      int k2 = cid & 7;
      int gran = c64 * 16 + (k2 >> 1) * 4 + ntb + (k2 & 1);
      const __bf16* src = (cid < 8 ? phi : plo) + (size_t)gran * 512 + lane * 8;
      GLOAD_LDS16(src, &ldsB[buf][cid * 1024]);
    }
  };

  stage(0, 0);
  __syncthreads();   // compiler drains vmcnt before s_barrier -> stage done

  for (int ch = 0; ch < 64; ++ch) {
    const int buf = ch & 1;
    if (ch < 63) stage(ch + 1, buf ^ 1);   // in flight under this chunk's MFMA

    f32x4 acc[2];
#pragma unroll
    for (int mt = 0; mt < 2; ++mt) acc[mt] = (f32x4){0.f, 0.f, 0.f, 0.f};

#pragma unroll
    for (int ks = 0; ks < 4; ++ks) {
      // conflict-free: 64 lanes read consecutive 16B (2 lanes/bank = free)
      bf16x8 bh = *(const bf16x8*)&ldsB[buf][(ks * 2 + wc) * 1024 + lane * 16];
      bf16x8 bl = *(const bf16x8*)&ldsB[buf][(8 + ks * 2 + wc) * 1024 + lane * 16];
#pragma unroll
      for (int mt = 0; mt < 2; ++mt) {
        acc[mt] = __builtin_amdgcn_mfma_f32_16x16x32_bf16(al[mt][ks], bh, acc[mt], 0, 0, 0);
        acc[mt] = __builtin_amdgcn_mfma_f32_16x16x32_bf16(ah[mt][ks], bl, acc[mt], 0, 0, 0);
        acc[mt] = __builtin_amdgcn_mfma_f32_16x16x32_bf16(ah[mt][ks], bh, acc[mt], 0, 0, 0);
      }
    }

    // ---- Fold dist into running state (branchless). Lane's candidate code
    // ascends strictly with ch -> strict < keeps first index.
    const int ci = ch * 32 + wc * 16 + col;
    const float l2 = l2k[ci];
#pragma unroll
    for (int mt = 0; mt < 2; ++mt) {
#pragma unroll
      for (int r = 0; r < 4; ++r) {
        float dd = fmaf(-2.0f, acc[mt][r], l2);
        bool lt = dd < m1[mt][r];
        m2[mt][r] = lt ? m1[mt][r] : fminf(m2[mt][r], dd);
        bi[mt][r] = lt ? ci : bi[mt][r];
        m1[mt][r] = fminf(m1[mt][r], dd);
      }
    }

    // 2-phase handoff: all reads of buf done + next stage drained
    __syncthreads();
  }

  // ---- Cross-lane reduction: 16 cols per quad-row ----
#pragma unroll
  for (int mt = 0; mt < 2; ++mt) {
#pragma unroll
    for (int r = 0; r < 4; ++r) {
      float b = m1[mt][r], s = m2[mt][r];
      int i = bi[mt][r];
#pragma unroll
      for (int m = 1; m < 16; m <<= 1) {
        float ob = __shfl_xor(b, m);
        float os = __shfl_xor(s, m);
        int oi = __shfl_xor(i, m);
        merge_bs(b, s, i, ob, os, oi);
      }
      if (col == 0) {
        int qloc = 16 * mt + 4 * quad + r;
        redB[wv][qloc] = b;
        redS[wv][qloc] = s;
        redI[wv][qloc] = i;
      }
    }
  }
  __syncthreads();

  // ---- Final merge across the 2 code-slice waves of each query half ----
  if (tid < QB) {
    int wq2 = tid >> 5;           // which query half
    int ql = tid & 31;
    float b = 3.4e38f, s = 3.4e38f;
    int i = 0x7fffffff;
    merge_bs(b, s, i, redB[wq2 * 2 + 0][ql], redS[wq2 * 2 + 0][ql], redI[wq2 * 2 + 0][ql]);
    merge_bs(b, s, i, redB[wq2 * 2 + 1][ql], redS[wq2 * 2 + 1][ql], redI[wq2 * 2 + 1][ql]);
    best_idx[q0 + tid] = i;
    if (s - b < MARGIN) {
      int pos = atomicAdd(flag_count, 1);
      flagged[pos] = q0 + tid;
    }
  }
}

// ---------------------------------------------------------------------------
// Fixup: for flagged queries, emulate the reference's fp32 computation:
//   dist = fl32( fl32(l2q32 + l2k32[c]) - fl32(2 * fl32(q.k)) )
// q.k exact in fp64 then rounded once to fp32. First-index tie-break.
// ---------------------------------------------------------------------------
__global__ __launch_bounds__(256) void fixup_kernel(const float* __restrict__ x,
                                                    const float* __restrict__ w,
                                                    const float* __restrict__ l2k32,
                                                    const int* __restrict__ flagged,
                                                    const int* __restrict__ flag_count,
                                                    int* __restrict__ best_idx) {
  __shared__ float qs[D_DIM];
  __shared__ float l2q_sh;
  __shared__ float redD[256];
  __shared__ int redI[256];
  const int tid = threadIdx.x;
  const int n = *flag_count;
  for (int f = blockIdx.x; f < n; f += gridDim.x) {
    __syncthreads();
    int q = flagged[f];
    if (tid < D_DIM) qs[tid] = x[(size_t)q * D_DIM + tid];
    __syncthreads();
    if (tid == 0) {
      double s = 0.0;
      for (int d = 0; d < D_DIM; ++d) {
        float t = qs[d] * qs[d];
        s += (double)t;
      }
      l2q_sh = (float)s;
    }
    __syncthreads();
    const float l2q = l2q_sh;
    float bd = 3.4e38f;
    int bi = 0x7fffffff;
    for (int c = tid; c < M_CODES; c += 256) {
      const float4* wr = (const float4*)(w + (size_t)c * D_DIM);
      double s = 0.0;
#pragma unroll
      for (int j = 0; j < 32; ++j) {
        float4 v = wr[j];
        s = fma((double)qs[j * 4 + 0], (double)v.x, s);
        s = fma((double)qs[j * 4 + 1], (double)v.y, s);
        s = fma((double)qs[j * 4 + 2], (double)v.z, s);
        s = fma((double)qs[j * 4 + 3], (double)v.w, s);
      }
      float simf = (float)s;
      float S = l2q + l2k32[c];
      float T = 2.0f * simf;
      float dist = S - T;
      if (dist < bd) { bd = dist; bi = c; }
    }
    redD[tid] = bd;
    redI[tid] = bi;
    __syncthreads();
    for (int off = 128; off; off >>= 1) {
      if (tid < off) {
        float od = redD[tid + off];
        int oi = redI[tid + off];
        if (od < redD[tid] || (od == redD[tid] && oi < redI[tid])) {
          redD[tid] = od;
          redI[tid] = oi;
        }
      }
      __syncthreads();
    }
    if (tid == 0) best_idx[q] = redI[0];
  }
}

// ---------------------------------------------------------------------------
// Gather + straight-through output + loss partials + histogram + indices out
// ---------------------------------------------------------------------------
__global__ __launch_bounds__(256) void epilogue_kernel(const float* __restrict__ x,
                                                       const float* __restrict__ w,
                                                       const int* __restrict__ best_idx,
                                                       float* __restrict__ out,
                                                       float* __restrict__ part,
                                                       int* __restrict__ counts) {
  int gid = blockIdx.x * 256 + threadIdx.x;  // float4 id, 2,097,152 total
  int q = gid >> 5;
  int d4 = gid & 31;
  int idx = best_idx[q];
  float4 xv = ((const float4*)x)[gid];
  float4 wv = ((const float4*)w)[(size_t)idx * 32 + d4];
  float4 o;
  float t0 = wv.x - xv.x; o.x = xv.x + t0; float e0 = o.x - xv.x;
  float t1 = wv.y - xv.y; o.y = xv.y + t1; float e1 = o.y - xv.y;
  float t2 = wv.z - xv.z; o.z = xv.z + t2; float e2 = o.z - xv.z;
  float t3 = wv.w - xv.w; o.w = xv.w + t3; float e3 = o.w - xv.w;
  float ls = e0 * e0 + e1 * e1 + e2 * e2 + e3 * e3;
  ((float4*)out)[gid] = o;

  for (int off = 32; off; off >>= 1) ls += __shfl_down(ls, off);
  __shared__ float red[4];
  if ((threadIdx.x & 63) == 0) red[threadIdx.x >> 6] = ls;
  __syncthreads();
  if (threadIdx.x == 0) part[blockIdx.x] = red[0] + red[1] + red[2] + red[3];

  if (d4 == 0) {
    out[OUT_IDX + q] = (float)idx;
    atomicAdd(&counts[idx], 1);
  }
}

// ---------------------------------------------------------------------------
// Finalize: loss mean + perplexity
// ---------------------------------------------------------------------------
__global__ __launch_bounds__(256) void finalize_kernel(const int* __restrict__ counts,
                                                       const float* __restrict__ part,
                                                       float* __restrict__ out) {
  int tid = threadIdx.x;
  float ls = 0.f;
  for (int i = tid; i < 8192; i += 256) ls += part[i];
  float es = 0.f;
  for (int i = tid; i < M_CODES; i += 256) {
    float p = (float)counts[i] * (1.0f / 65536.0f);
    es += p * logf(p + 1e-10f);
  }
  for (int off = 32; off; off >>= 1) {
    ls += __shfl_down(ls, off);
    es += __shfl_down(es, off);
  }
  __shared__ float redl[4], rede[4];
  if ((tid & 63) == 0) {
    redl[tid >> 6] = ls;
    rede[tid >> 6] = es;
  }
  __syncthreads();
  if (tid == 0) {
    out[OUT_LOSS] = (redl[0] + redl[1] + redl[2] + redl[3]) * (1.0f / 8388608.0f);
    out[OUT_PERP] = expf(-(rede[0] + rede[1] + rede[2] + rede[3]));
  }
}

extern "C" void kernel_launch(void* const* d_in, const int* in_sizes, int n_in,
                              void* d_out, int out_size, void* d_ws, size_t ws_size,
                              hipStream_t stream) {
  const float* x = (const float*)d_in[0];
  const float* w = (const float*)d_in[1];
  float* out = (float*)d_out;
  char* ws = (char*)d_ws;
  float* l2k = (float*)(ws + WS_L2K);
  __bf16* phi = (__bf16*)(ws + WS_PHI);
  __bf16* plo = (__bf16*)(ws + WS_PLO);
  int* bidx = (int*)(ws + WS_IDX);
  float* part = (float*)(ws + WS_PART);
  int* counts = (int*)(ws + WS_CNT);
  int* flagcnt = (int*)(ws + WS_FLAGCNT);
  int* flagged = (int*)(ws + WS_FLAGGED);

  hipMemsetAsync(counts, 0, M_CODES * sizeof(int), stream);
  hipMemsetAsync(flagcnt, 0, sizeof(int), stream);
  l2_kernel<<<8, 256, 0, stream>>>(w, l2k);
  pack_w_frag<<<128, 256, 0, stream>>>(w, phi, plo);
  argmin_mfma<<<BN_TOT / QB, 256, 0, stream>>>(x, phi, plo, l2k, bidx, flagcnt, flagged);
  fixup_kernel<<<256, 256, 0, stream>>>(x, w, l2k, flagged, flagcnt, bidx);
  epilogue_kernel<<<8192, 256, 0, stream>>>(x, w, bidx, out, part, counts);
  finalize_kernel<<<1, 256, 0, stream>>>(counts, part, out);
}